// Round 1
// baseline (178.613 us; speedup 1.0000x reference)
//
#include <hip/hip_runtime.h>

#define N 1024
#define DIM 128

// Kernel 1: Q = x@W_Q+b_Q, K = x@W_K+b_K, V = x@W_V+b_V.
// One block per row i, 128 threads (thread = output column d).
// W is [in][out] row-major, so W[c*DIM+d] is coalesced in d.
__global__ __launch_bounds__(128) void qkv_kernel(
    const float* __restrict__ x,
    const float* __restrict__ WQ, const float* __restrict__ bQ,
    const float* __restrict__ WK, const float* __restrict__ bK,
    const float* __restrict__ WV, const float* __restrict__ bV,
    float* __restrict__ Q, float* __restrict__ K, float* __restrict__ V) {
  const int i = blockIdx.x;
  const int d = threadIdx.x;
  __shared__ float xs[DIM];
  xs[d] = x[i * DIM + d];
  __syncthreads();
  float q = bQ[d], k = bK[d], v = bV[d];
  for (int c = 0; c < DIM; ++c) {
    const float xv = xs[c];  // LDS broadcast, conflict-free
    q = fmaf(xv, WQ[c * DIM + d], q);
    k = fmaf(xv, WK[c * DIM + d], k);
    v = fmaf(xv, WV[c * DIM + d], v);
  }
  Q[i * DIM + d] = q;
  K[i * DIM + d] = k;
  V[i * DIM + d] = v;
}

// Kernel 2: per row i —
//   e_j   = sum_d relu(Q_i[d]+K_j[d]) * W_A[d]        (b_A dropped: softmax-invariant)
//   p_j   = exp(e_j - max)
//   R[d]  = sum_j p_j * relu(Q_i[d]+K_j[d])
//   S[d]  = sum_j p_j * V_j[d]
//   out_i = (S + R @ W_Ev) / sum(p) + b_Ev
__global__ __launch_bounds__(256) void attn_kernel(
    const float* __restrict__ Q, const float* __restrict__ K,
    const float* __restrict__ V, const float* __restrict__ WA,
    const float* __restrict__ WEv, const float* __restrict__ bEv,
    float* __restrict__ out) {
  const int i = blockIdx.x;
  const int t = threadIdx.x;

  __shared__ __align__(16) float qs[DIM];
  __shared__ __align__(16) float was[DIM];
  __shared__ __align__(16) float p[N];       // e_j, then p_j (unnormalized)
  __shared__ float red[256];
  __shared__ __align__(16) float Rs[8][DIM]; // per-ty partial R
  __shared__ __align__(16) float Ss[8][DIM]; // per-ty partial S

  if (t < DIM) {
    qs[t] = Q[i * DIM + t];
    was[t] = WA[t];
  }
  __syncthreads();

  // ---- pass 1: e_j for j = t, t+256, t+512, t+768 ----
  float evals[4];
  float mloc = -3.4e38f;
  for (int jj = 0; jj < 4; ++jj) {
    const int j = t + jj * 256;
    const float4* krow = (const float4*)(K + j * DIM);
    const float4* q4p = (const float4*)qs;
    const float4* w4p = (const float4*)was;
    float acc = 0.f;
    for (int d4 = 0; d4 < DIM / 4; ++d4) {
      const float4 k4 = krow[d4];
      const float4 q4 = q4p[d4];
      const float4 w4 = w4p[d4];
      acc = fmaf(fmaxf(q4.x + k4.x, 0.f), w4.x, acc);
      acc = fmaf(fmaxf(q4.y + k4.y, 0.f), w4.y, acc);
      acc = fmaf(fmaxf(q4.z + k4.z, 0.f), w4.z, acc);
      acc = fmaf(fmaxf(q4.w + k4.w, 0.f), w4.w, acc);
    }
    evals[jj] = acc;
    mloc = fmaxf(mloc, acc);
  }

  // ---- block max reduction ----
  red[t] = mloc;
  __syncthreads();
  for (int s = 128; s > 0; s >>= 1) {
    if (t < s) red[t] = fmaxf(red[t], red[t + s]);
    __syncthreads();
  }
  const float m = red[0];
  __syncthreads();  // everyone has read red[0] before reuse

  // ---- exp + sum ----
  float lsum = 0.f;
  for (int jj = 0; jj < 4; ++jj) {
    const float pe = __expf(evals[jj] - m);
    p[t + jj * 256] = pe;
    lsum += pe;
  }
  red[t] = lsum;
  __syncthreads();
  for (int s = 128; s > 0; s >>= 1) {
    if (t < s) red[t] += red[t + s];
    __syncthreads();
  }
  const float linv = 1.0f / red[0];
  __syncthreads();  // p[] fully written + red consumed before pass 2

  // ---- pass 2: weighted accumulation, coalesced over d ----
  const int tx = t & 31;   // d-quad: d = 4*tx .. 4*tx+3
  const int ty = t >> 5;   // j-phase 0..7
  const float4 q4 = ((const float4*)qs)[tx];
  float4 R4 = make_float4(0.f, 0.f, 0.f, 0.f);
  float4 S4 = make_float4(0.f, 0.f, 0.f, 0.f);
  for (int j = ty; j < N; j += 8) {
    const float pj = p[j];
    const float4 k4 = ((const float4*)(K + j * DIM))[tx];
    const float4 v4 = ((const float4*)(V + j * DIM))[tx];
    R4.x = fmaf(pj, fmaxf(q4.x + k4.x, 0.f), R4.x);
    R4.y = fmaf(pj, fmaxf(q4.y + k4.y, 0.f), R4.y);
    R4.z = fmaf(pj, fmaxf(q4.z + k4.z, 0.f), R4.z);
    R4.w = fmaf(pj, fmaxf(q4.w + k4.w, 0.f), R4.w);
    S4.x = fmaf(pj, v4.x, S4.x);
    S4.y = fmaf(pj, v4.y, S4.y);
    S4.z = fmaf(pj, v4.z, S4.z);
    S4.w = fmaf(pj, v4.w, S4.w);
  }
  ((float4*)&Rs[ty][0])[tx] = R4;
  ((float4*)&Ss[ty][0])[tx] = S4;
  __syncthreads();

  // ---- reduce the 8 j-phases; stash full R,S vectors in row 0 ----
  if (t < DIM) {
    float R = 0.f, S = 0.f;
    for (int g = 0; g < 8; ++g) {
      R += Rs[g][t];
      S += Ss[g][t];
    }
    Rs[0][t] = R;
    Ss[0][t] = S;
  }
  __syncthreads();

  // ---- epilogue: out[d] = (S[d] + sum_d' R[d']*WEv[d'][d]) * linv + bEv[d] ----
  if (t < DIM) {
    float o = Ss[0][t];
    for (int dp = 0; dp < DIM; ++dp) {
      o = fmaf(Rs[0][dp], WEv[dp * DIM + t], o);  // Rs broadcast, WEv coalesced
    }
    out[i * DIM + t] = fmaf(o, linv, bEv[t]);
  }
}

extern "C" void kernel_launch(void* const* d_in, const int* in_sizes, int n_in,
                              void* d_out, int out_size, void* d_ws, size_t ws_size,
                              hipStream_t stream) {
  const float* x    = (const float*)d_in[0];
  const float* W_Q  = (const float*)d_in[1];
  const float* b_Q  = (const float*)d_in[2];
  const float* W_K  = (const float*)d_in[3];
  const float* b_K  = (const float*)d_in[4];
  const float* W_V  = (const float*)d_in[5];
  const float* b_V  = (const float*)d_in[6];
  const float* W_Ev = (const float*)d_in[7];
  const float* b_Ev = (const float*)d_in[8];
  const float* W_A  = (const float*)d_in[9];
  // d_in[10] = b_A: constant shift under softmax — provably drops out.

  float* Q = (float*)d_ws;           // N*DIM
  float* K = Q + N * DIM;            // N*DIM
  float* V = K + N * DIM;            // N*DIM  (total 1.5 MB of ws)
  float* out = (float*)d_out;

  qkv_kernel<<<N, DIM, 0, stream>>>(x, W_Q, b_Q, W_K, b_K, W_V, b_V, Q, K, V);
  attn_kernel<<<N, 256, 0, stream>>>(Q, K, V, W_A, W_Ev, b_Ev, out);
}